// Round 4
// baseline (194.364 us; speedup 1.0000x reference)
//
#include <hip/hip_runtime.h>
#include <math.h>

#define TAU_CONST 1.0f
#define BLOCK 256
#define NBLOCKS 1024   // 4 blocks/CU on 256 CUs; persistent grid-stride

typedef float vfloat4 __attribute__((ext_vector_type(4)));

__device__ __forceinline__ float fast_rcp(float x) { return __builtin_amdgcn_rcpf(x); }

__device__ __forceinline__ float kld_row(const float* p, const float* t) {
    float pw = fminf(fmaxf(p[2], 1e-7f), 1e7f), ph = fminf(fmaxf(p[3], 1e-7f), 1e7f);
    float tw = fminf(fmaxf(t[2], 1e-7f), 1e7f), th = fminf(fmaxf(t[3], 1e-7f), 1e7f);
    float ap = 0.25f * pw * pw, bp = 0.25f * ph * ph;
    float at = 0.25f * tw * tw, bt = 0.25f * th * th;
    float sp_, cp_; __sincosf(p[4], &sp_, &cp_);
    float st_, ct_; __sincosf(t[4], &st_, &ct_);
    float p00 = ap * cp_ * cp_ + bp * sp_ * sp_;
    float p11 = ap * sp_ * sp_ + bp * cp_ * cp_;
    float p01 = (ap - bp) * sp_ * cp_;
    float t00 = at * ct_ * ct_ + bt * st_ * st_;
    float t11 = at * st_ * st_ + bt * ct_ * ct_;
    float t01 = (at - bt) * st_ * ct_;
    float dp = p00 * p11 - p01 * p01;
    float dt = t00 * t11 - t01 * t01;
    float dx = p[0] - t[0], dy = p[1] - t[1];
    float inv_dt = fast_rcp(dt);
    float term1 = (dx * dx * t11 - 2.0f * dx * dy * t01 + dy * dy * t00) * inv_dt;
    float tr    = (t11 * p00 + t00 * p11 - 2.0f * t01 * p01) * inv_dt;
    float term2 = tr + (__logf(dt) - __logf(dp));
    float dis = term1 + term2 - 2.0f;
    float kl = fmaxf(dis, 1e-6f);
    return 1.0f - fast_rcp(TAU_CONST + __logf(1.0f + kl));
}

__device__ __forceinline__ void load_tile(const vfloat4* __restrict__ p4,
                                          const vfloat4* __restrict__ t4,
                                          int i, vfloat4* P, vfloat4* T) {
    const long b = 5L * i;
#pragma unroll
    for (int k = 0; k < 5; ++k) {
        P[k] = __builtin_nontemporal_load(p4 + b + k);
        T[k] = __builtin_nontemporal_load(t4 + b + k);
    }
}

// Persistent grid-stride kernel, 2-deep register pipeline: while computing
// tile i, the 10 nt loads for tile i+stride are already in flight. No LDS.
// Each "tile" = 4 consecutive rows = 5 vfloat4 per input.
__global__ void __launch_bounds__(BLOCK) gdloss_pipe_kernel(const vfloat4* __restrict__ pred4,
                                                            const vfloat4* __restrict__ targ4,
                                                            vfloat4* __restrict__ out4,
                                                            int n4) {
    const int stride = gridDim.x * blockDim.x;
    int i = blockIdx.x * blockDim.x + threadIdx.x;
    if (i >= n4) return;

    vfloat4 Pa[5], Ta[5], Pb[5], Tb[5];
    load_tile(pred4, targ4, i, Pa, Ta);

    while (true) {
        const int inext = i + stride;
        const bool more = (inext < n4);
        if (more) load_tile(pred4, targ4, inext, Pb, Tb);

        {
            const float* P = (const float*)Pa;
            const float* T = (const float*)Ta;
            vfloat4 o;
            o.x = kld_row(P + 0,  T + 0);
            o.y = kld_row(P + 5,  T + 5);
            o.z = kld_row(P + 10, T + 10);
            o.w = kld_row(P + 15, T + 15);
            __builtin_nontemporal_store(o, out4 + i);
        }
        if (!more) break;
        i = inext;

        const int inext2 = i + stride;
        const bool more2 = (inext2 < n4);
        if (more2) load_tile(pred4, targ4, inext2, Pa, Ta);

        {
            const float* P = (const float*)Pb;
            const float* T = (const float*)Tb;
            vfloat4 o;
            o.x = kld_row(P + 0,  T + 0);
            o.y = kld_row(P + 5,  T + 5);
            o.z = kld_row(P + 10, T + 10);
            o.w = kld_row(P + 15, T + 15);
            __builtin_nontemporal_store(o, out4 + i);
        }
        if (!more2) break;
        i = inext2;
    }
}

// Scalar tail for n % 4 rows (not hit at N=4M; kept for generality).
__global__ void gdloss_tail_kernel(const float* __restrict__ pred,
                                   const float* __restrict__ target,
                                   float* __restrict__ out, int start, int n) {
    int i = start + blockIdx.x * blockDim.x + threadIdx.x;
    if (i >= n) return;
    float p[5], t[5];
#pragma unroll
    for (int k = 0; k < 5; ++k) { p[k] = pred[5 * i + k]; t[k] = target[5 * i + k]; }
    out[i] = kld_row(p, t);
}

extern "C" void kernel_launch(void* const* d_in, const int* in_sizes, int n_in,
                              void* d_out, int out_size, void* d_ws, size_t ws_size,
                              hipStream_t stream) {
    const float* pred   = (const float*)d_in[0];
    const float* target = (const float*)d_in[1];
    float* out = (float*)d_out;
    const int n = in_sizes[0] / 5;   // rows
    const int n4 = n / 4;            // float4 output groups
    if (n4 > 0) {
        int blocks = (n4 + BLOCK - 1) / BLOCK;
        if (blocks > NBLOCKS) blocks = NBLOCKS;
        gdloss_pipe_kernel<<<blocks, BLOCK, 0, stream>>>((const vfloat4*)pred,
                                                         (const vfloat4*)target,
                                                         (vfloat4*)out, n4);
    }
    if (n - n4 * 4 > 0) {
        gdloss_tail_kernel<<<1, 64, 0, stream>>>(pred, target, out, n4 * 4, n);
    }
}

// Round 5
// 178.428 us; speedup vs baseline: 1.0893x; 1.0893x over previous
//
#include <hip/hip_runtime.h>
#include <math.h>

#define TAU_CONST 1.0f
#define BLOCK 256

#define INV_PI 0.31830988618f   // 1/pi : rev = r/pi -> v_sin(rev) = sin(2r)
#define LN2    0.69314718056f

__device__ __forceinline__ float fast_rcp(float x) { return __builtin_amdgcn_rcpf(x); }
__device__ __forceinline__ float fast_log2(float x) { return __builtin_amdgcn_logf(x); }

// Pure-HW-instruction row loss: no ocml calls (the __sincosf scratch round-trip
// was the suspected serializer). Uses double-angle form:
//   s00 = (a+b)/2 + (a-b)/2 * cos2r,  s11 = (a+b)/2 - (a-b)/2 * cos2r,
//   s01 = (a-b)/2 * sin2r,            det = a*b (exact, rotation-invariant).
__device__ __forceinline__ float kld_row(const float* p, const float* t) {
    float pw = fminf(fmaxf(p[2], 1e-7f), 1e7f), ph = fminf(fmaxf(p[3], 1e-7f), 1e7f);
    float tw = fminf(fmaxf(t[2], 1e-7f), 1e7f), th = fminf(fmaxf(t[3], 1e-7f), 1e7f);
    float ap = 0.25f * pw * pw, bp = 0.25f * ph * ph;
    float at = 0.25f * tw * tw, bt = 0.25f * th * th;

    // v_sin/v_cos take revolutions; r in (-pi/2,pi/2) -> rev in (-0.5,0.5), no fract needed.
    float revp = p[4] * INV_PI;
    float revt = t[4] * INV_PI;
    float s2p = __builtin_amdgcn_sinf(revp), c2p = __builtin_amdgcn_cosf(revp);
    float s2t = __builtin_amdgcn_sinf(revt), c2t = __builtin_amdgcn_cosf(revt);

    float hp = 0.5f * (ap + bp), qp = 0.5f * (ap - bp);
    float ht = 0.5f * (at + bt), qt = 0.5f * (at - bt);
    float p00 = hp + qp * c2p, p11 = hp - qp * c2p, p01 = qp * s2p;
    float t00 = ht + qt * c2t, t11 = ht - qt * c2t, t01 = qt * s2t;

    float dp = ap * bp;            // det(sigma_p), exact
    float dt = at * bt;            // det(sigma_t), exact
    float inv_dt = fast_rcp(dt);

    float dx = p[0] - t[0], dy = p[1] - t[1];
    float term1 = (dx * dx * t11 - 2.0f * dx * dy * t01 + dy * dy * t00) * inv_dt;
    float tr    = (t11 * p00 + t00 * p11 - 2.0f * t01 * p01) * inv_dt;
    float logterm = LN2 * fast_log2(dt * fast_rcp(dp));

    float dis = term1 + tr + logterm - 2.0f;
    float kl  = fmaxf(dis, 1e-6f);
    float denom = TAU_CONST + LN2 * fast_log2(1.0f + kl);
    return 1.0f - fast_rcp(denom);
}

// One thread = 4 consecutive rows = 5 float4 loads per input + 1 float4 store.
__global__ void __launch_bounds__(BLOCK) gdloss_hw_kernel(const float4* __restrict__ pred4,
                                                          const float4* __restrict__ targ4,
                                                          float4* __restrict__ out4, int n4) {
    int tid = blockIdx.x * blockDim.x + threadIdx.x;
    if (tid >= n4) return;
    float4 pv[5], tv[5];
    const long b = 5L * tid;
#pragma unroll
    for (int k = 0; k < 5; ++k) {
        pv[k] = pred4[b + k];
        tv[k] = targ4[b + k];
    }
    const float* P = (const float*)pv;
    const float* T = (const float*)tv;
    float4 o;
    o.x = kld_row(P + 0,  T + 0);
    o.y = kld_row(P + 5,  T + 5);
    o.z = kld_row(P + 10, T + 10);
    o.w = kld_row(P + 15, T + 15);
    out4[tid] = o;
}

// Scalar tail for n % 4 rows (not hit at N=4M; kept for generality).
__global__ void gdloss_tail_kernel(const float* __restrict__ pred,
                                   const float* __restrict__ target,
                                   float* __restrict__ out, int start, int n) {
    int i = start + blockIdx.x * blockDim.x + threadIdx.x;
    if (i >= n) return;
    float p[5], t[5];
#pragma unroll
    for (int k = 0; k < 5; ++k) { p[k] = pred[5 * i + k]; t[k] = target[5 * i + k]; }
    out[i] = kld_row(p, t);
}

extern "C" void kernel_launch(void* const* d_in, const int* in_sizes, int n_in,
                              void* d_out, int out_size, void* d_ws, size_t ws_size,
                              hipStream_t stream) {
    const float* pred   = (const float*)d_in[0];
    const float* target = (const float*)d_in[1];
    float* out = (float*)d_out;
    const int n = in_sizes[0] / 5;   // rows
    const int n4 = n / 4;            // float4 output groups
    if (n4 > 0) {
        int blocks = (n4 + BLOCK - 1) / BLOCK;
        gdloss_hw_kernel<<<blocks, BLOCK, 0, stream>>>((const float4*)pred,
                                                       (const float4*)target,
                                                       (float4*)out, n4);
    }
    if (n - n4 * 4 > 0) {
        gdloss_tail_kernel<<<1, 64, 0, stream>>>(pred, target, out, n4 * 4, n);
    }
}